// Round 1
// 95.438 us; speedup vs baseline: 1.0214x; 1.0214x over previous
//
#include <hip/hip_runtime.h>
#include <hip/hip_bf16.h>

#define TGT   64
#define SRCN  64
#define BATCH 32
#define HID   512
#define ATT   512
#define MROWS (TGT * BATCH)          // 2048 rows per z

typedef __bf16 bf16_t;
typedef __bf16 bf16x8 __attribute__((ext_vector_type(8)));
typedef float  f32x4  __attribute__((ext_vector_type(4)));

// HW transcendentals (round-3 lesson: libm exp2f/__frcp_rn cost 29 us).
__device__ __forceinline__ float fast_exp2(float x) {
#if __has_builtin(__builtin_amdgcn_exp2f)
  return __builtin_amdgcn_exp2f(x);
#else
  float r; asm("v_exp_f32 %0, %1\n\ts_nop 1" : "=v"(r) : "v"(x)); return r;
#endif
}
__device__ __forceinline__ float fast_rcp(float x) {
#if __has_builtin(__builtin_amdgcn_rcpf)
  return __builtin_amdgcn_rcpf(x);
#else
  float r; asm("v_rcp_f32 %0, %1\n\ts_nop 1" : "=v"(r) : "v"(x)); return r;
#endif
}

#define MFMA(a, b, c) __builtin_amdgcn_mfma_f32_16x16x32_bf16((a), (b), (c), 0, 0, 0)

#define SC_EXP 2.8853900817779268f   // 2*log2(e): e^(2v) == exp2(SC_EXP*v)

// ---------------------------------------------------------------------------
// proj_gemm v3:
//   - software-pipelined global loads: tile k+1 prefetched into registers
//     right after the store->read barrier, retires under the MFMA phase
//     (the compiler's vmcnt(0) drain at the next top-of-loop barrier is
//     exactly where the data is first consumed).
//   - epilogue stores exp2(SC*acc) instead of acc: attn consumes ONLY the
//     exponentials, so the 16.8M exp2 in attn's hot loop collapse to 2.1M
//     here, latency-hidden behind the accumulator drain.
// ---------------------------------------------------------------------------
__global__ __launch_bounds__(256) void proj_gemm(
    const float* __restrict__ h_t, const float* __restrict__ srcp,
    const float* __restrict__ Wa, float* __restrict__ C)
{
  const int z = blockIdx.z;
  const float* __restrict__ A = z ? srcp : h_t;
  const int mbase = blockIdx.x * 64;
  const int nbase = blockIdx.y * 64;

  __shared__ bf16_t Ah[64][72];
  __shared__ bf16_t Al[64][72];
  __shared__ bf16_t Bh[64][72];   // transposed: Bh[n][k]
  __shared__ bf16_t Bl[64][72];

  const int tid  = threadIdx.x;
  const int lane = tid & 63;
  const int wv   = tid >> 6;          // 0..3
  const int wm   = (wv & 1) * 32;
  const int wn   = (wv >> 1) * 32;
  const int l15  = lane & 15;
  const int qd   = lane >> 4;

  const int arow = tid >> 2;
  const int akc  = (tid & 3) * 16;
  const int bn = tid & 63;
  const int bkg = (tid >> 6) * 16;

  const float* Aptr = A + (size_t)(mbase + arow) * HID + akc;
  const float* Bptr = Wa + (size_t)(z * HID + bkg) * ATT + nbase + bn;

  f32x4 acc00 = {0.f, 0.f, 0.f, 0.f};
  f32x4 acc01 = acc00, acc10 = acc00, acc11 = acc00;

  // ---- prefetch tile kb=0 into registers ----
  float4 pa0 = *(const float4*)(Aptr);
  float4 pa1 = *(const float4*)(Aptr + 4);
  float4 pa2 = *(const float4*)(Aptr + 8);
  float4 pa3 = *(const float4*)(Aptr + 12);
  float pb[16];
#pragma unroll
  for (int j = 0; j < 16; ++j) pb[j] = Bptr[(size_t)j * ATT];

  for (int kb = 0; kb < HID; kb += 64) {
    if (kb) __syncthreads();          // prev MFMA reads done before overwrite

    {
      float av[16] = {pa0.x, pa0.y, pa0.z, pa0.w, pa1.x, pa1.y, pa1.z, pa1.w,
                      pa2.x, pa2.y, pa2.z, pa2.w, pa3.x, pa3.y, pa3.z, pa3.w};
      bf16x8 hi0, hi1, lo0, lo1;
#pragma unroll
      for (int j = 0; j < 8; ++j) {
        bf16_t h = (bf16_t)av[j];
        hi0[j] = h;
        lo0[j] = (bf16_t)(av[j] - (float)h);
        bf16_t h2 = (bf16_t)av[j + 8];
        hi1[j] = h2;
        lo1[j] = (bf16_t)(av[j + 8] - (float)h2);
      }
      *(bf16x8*)&Ah[arow][akc]     = hi0;
      *(bf16x8*)&Ah[arow][akc + 8] = hi1;
      *(bf16x8*)&Al[arow][akc]     = lo0;
      *(bf16x8*)&Al[arow][akc + 8] = lo1;
    }

    {
      bf16x8 hi0, hi1, lo0, lo1;
#pragma unroll
      for (int j = 0; j < 8; ++j) {
        bf16_t h = (bf16_t)pb[j];
        hi0[j] = h;
        lo0[j] = (bf16_t)(pb[j] - (float)h);
        bf16_t h2 = (bf16_t)pb[j + 8];
        hi1[j] = h2;
        lo1[j] = (bf16_t)(pb[j + 8] - (float)h2);
      }
      *(bf16x8*)&Bh[bn][bkg]     = hi0;
      *(bf16x8*)&Bh[bn][bkg + 8] = hi1;
      *(bf16x8*)&Bl[bn][bkg]     = lo0;
      *(bf16x8*)&Bl[bn][bkg + 8] = lo1;
    }
    __syncthreads();

    // ---- prefetch tile kb+64 (overlaps with MFMA phase below) ----
    const int kn = kb + 64;
    if (kn < HID) {
      pa0 = *(const float4*)(Aptr + kn);
      pa1 = *(const float4*)(Aptr + kn + 4);
      pa2 = *(const float4*)(Aptr + kn + 8);
      pa3 = *(const float4*)(Aptr + kn + 12);
      const float* bp = Bptr + (size_t)kn * ATT;
#pragma unroll
      for (int j = 0; j < 16; ++j) pb[j] = bp[(size_t)j * ATT];
    }

#pragma unroll
    for (int h = 0; h < 2; ++h) {
      const int kh = h * 32 + qd * 8;
      bf16x8 ah0 = *(const bf16x8*)&Ah[wm + l15][kh];
      bf16x8 ah1 = *(const bf16x8*)&Ah[wm + 16 + l15][kh];
      bf16x8 al0 = *(const bf16x8*)&Al[wm + l15][kh];
      bf16x8 al1 = *(const bf16x8*)&Al[wm + 16 + l15][kh];
      bf16x8 bh0 = *(const bf16x8*)&Bh[wn + l15][kh];
      bf16x8 bh1 = *(const bf16x8*)&Bh[wn + 16 + l15][kh];
      bf16x8 bl0 = *(const bf16x8*)&Bl[wn + l15][kh];
      bf16x8 bl1 = *(const bf16x8*)&Bl[wn + 16 + l15][kh];

      acc00 = MFMA(ah0, bh0, acc00);
      acc01 = MFMA(ah0, bh1, acc01);
      acc10 = MFMA(ah1, bh0, acc10);
      acc11 = MFMA(ah1, bh1, acc11);
      acc00 = MFMA(al0, bh0, acc00);
      acc01 = MFMA(al0, bh1, acc01);
      acc10 = MFMA(al1, bh0, acc10);
      acc11 = MFMA(al1, bh1, acc11);
      acc00 = MFMA(ah0, bl0, acc00);
      acc01 = MFMA(ah0, bl1, acc01);
      acc10 = MFMA(ah1, bl0, acc10);
      acc11 = MFMA(ah1, bl1, acc11);
    }
  }

  // ---- epilogue: store exp2(SC*acc) (attn only ever consumes e^{2v}) ----
  float* Cz = C + (size_t)z * (MROWS * ATT);
#pragma unroll
  for (int r = 0; r < 4; ++r) {
    int row0 = mbase + wm + qd * 4 + r;
    int row1 = row0 + 16;
    int col0 = nbase + wn + l15;
    Cz[(size_t)row0 * ATT + col0]      = fast_exp2(acc00[r] * SC_EXP);
    Cz[(size_t)row0 * ATT + col0 + 16] = fast_exp2(acc01[r] * SC_EXP);
    Cz[(size_t)row1 * ATT + col0]      = fast_exp2(acc10[r] * SC_EXP);
    Cz[(size_t)row1 * ATT + col0 + 16] = fast_exp2(acc11[r] * SC_EXP);
  }
}

// ---------------------------------------------------------------------------
// attn_fused v5:
//   - workspace now holds exp2(SC*h_part) / exp2(SC*s_part): ZERO exp2 in
//     the score loop (was 8/row/lane).  Trans ops/element: 0.75 -> 0.5.
//   - multiplexed cross-lane reduction: all 4 targets reduced in ONE 6-step
//     tree (2 value-swapping folds route t into 16-lane quadrants, then 4
//     butterfly steps).  48 shfl-steps/row -> 12.
// Block = (4 targets, b), 512 thr, 8 waves; wave w handles s-rows w*8..w*8+7.
// ---------------------------------------------------------------------------
__global__ __launch_bounds__(512) void attn_fused(
    const float* __restrict__ ws, const float* __restrict__ srcp,
    const float* __restrict__ Va, float* __restrict__ out)
{
  const float* __restrict__ eh_part = ws;                              // exp2 domain
  const float* __restrict__ es_part = ws + (size_t)TGT * BATCH * ATT;  // exp2 domain

  const int t0   = blockIdx.x * 4;
  const int b    = blockIdx.y;
  const int tid  = threadIdx.x;
  const int lane = tid & 63;
  const int wv   = tid >> 6;              // 0..7

  __shared__ float scoreLds[4][64];
  __shared__ float attnLds[4][64];

  const int abase = lane * 8;
  float va[8], eH[4][8];
  *(float4*)&va[0] = *(const float4*)(Va + abase);
  *(float4*)&va[4] = *(const float4*)(Va + abase + 4);

  float vsum = 0.f;
#pragma unroll
  for (int j = 0; j < 8; ++j) vsum += va[j];
#pragma unroll
  for (int off = 32; off; off >>= 1) vsum += __shfl_xor(vsum, off);

#pragma unroll
  for (int t = 0; t < 4; ++t) {
    const float* hp = eh_part + ((size_t)(t0 + t) * BATCH + b) * ATT + abase;
    *(float4*)&eH[t][0] = *(const float4*)hp;
    *(float4*)&eH[t][4] = *(const float4*)(hp + 4);
  }

  const bool hi32 = (lane & 32) != 0;
  const bool hi16 = (lane & 16) != 0;

  // ---- scores: 8 s-rows per wave ----
#pragma unroll 2
  for (int i = 0; i < 8; ++i) {
    const int s = wv * 8 + i;
    const float* sp = es_part + ((size_t)s * BATCH + b) * ATT + abase;
    float ex[8];
    *(float4*)&ex[0] = *(const float4*)sp;
    *(float4*)&ex[4] = *(const float4*)(sp + 4);

    float q0 = 0.f, q1 = 0.f, q2 = 0.f, q3 = 0.f;
#pragma unroll
    for (int j = 0; j < 8; ++j) {
      float e = ex[j];
      float vj = va[j];
      float y0 = fmaf(e, eH[0][j], 1.0f);
      float y1 = fmaf(e, eH[1][j], 1.0f);
      float y2 = fmaf(e, eH[2][j], 1.0f);
      float y3 = fmaf(e, eH[3][j], 1.0f);
      float r01 = fast_rcp(y0 * y1);
      float r23 = fast_rcp(y2 * y3);
      q0 = fmaf(vj * y1, r01, q0);
      q1 = fmaf(vj * y0, r01, q1);
      q2 = fmaf(vj * y3, r23, q2);
      q3 = fmaf(vj * y2, r23, q3);
    }

    // multiplexed reduce: {q0,q1,q2,q3} summed over 64 lanes in 6 steps.
    // fold xor-32: lanes<32 accumulate q0 (resp. q1), lanes>=32 get q2 (q3)
    float a02 = hi32 ? q2 : q0;
    float b02 = hi32 ? q0 : q2;
    float a13 = hi32 ? q3 : q1;
    float b13 = hi32 ? q1 : q3;
    a02 += __shfl_xor(b02, 32);
    a13 += __shfl_xor(b13, 32);
    // fold xor-16: quadrant (lane>>4) == target index
    float x = hi16 ? a13 : a02;
    float y = hi16 ? a02 : a13;
    x += __shfl_xor(y, 16);
    // butterfly within 16-lane quadrant
    x += __shfl_xor(x, 8);
    x += __shfl_xor(x, 4);
    x += __shfl_xor(x, 2);
    x += __shfl_xor(x, 1);
    if ((lane & 15) == 0) scoreLds[lane >> 4][s] = vsum - 2.0f * x;
  }
  __syncthreads();

  // ---- softmax over s: waves 0..3 handle t = wv, lane = s ----
  if (wv < 4) {
    float sc = scoreLds[wv][lane];
    float m = sc;
#pragma unroll
    for (int off = 32; off; off >>= 1) m = fmaxf(m, __shfl_xor(m, off));
    float e = fast_exp2((sc - m) * 1.4426950408889634f);
    float ssum = e;
#pragma unroll
    for (int off = 32; off; off >>= 1) ssum += __shfl_xor(ssum, off);
    attnLds[wv][lane] = e * fast_rcp(ssum);
  }
  __syncthreads();

  // ---- context: thread h = tid covers one of 512 hidden dims ----
  {
    float c0 = 0.f, c1 = 0.f, c2 = 0.f, c3 = 0.f;
    const float* sb = srcp + (size_t)b * HID + tid;
#pragma unroll 8
    for (int s = 0; s < SRCN; ++s) {
      float sv = sb[(size_t)s * BATCH * HID];
      c0 = fmaf(attnLds[0][s], sv, c0);
      c1 = fmaf(attnLds[1][s], sv, c1);
      c2 = fmaf(attnLds[2][s], sv, c2);
      c3 = fmaf(attnLds[3][s], sv, c3);
    }
    out[((size_t)(t0 + 0) * BATCH + b) * HID + tid] = c0;
    out[((size_t)(t0 + 1) * BATCH + b) * HID + tid] = c1;
    out[((size_t)(t0 + 2) * BATCH + b) * HID + tid] = c2;
    out[((size_t)(t0 + 3) * BATCH + b) * HID + tid] = c3;
  }
}

extern "C" void kernel_launch(void* const* d_in, const int* in_sizes, int n_in,
                              void* d_out, int out_size, void* d_ws, size_t ws_size,
                              hipStream_t stream) {
  const float* h_t = (const float*)d_in[0];   // (64,32,512)
  const float* src = (const float*)d_in[1];   // (64,32,512)
  const float* Wa  = (const float*)d_in[2];   // (1024,512)
  const float* Va  = (const float*)d_in[3];   // (512,)
  float* out = (float*)d_out;                 // (64,32,512)
  float* C   = (float*)d_ws;                  // 8 MB: exp2(h_part)+exp2(s_part) fp32

  proj_gemm<<<dim3(32, 8, 2), 256, 0, stream>>>(h_t, src, Wa, C);
  attn_fused<<<dim3(16, 32), 512, 0, stream>>>(C, src, Va, out);
}